// Round 4
// baseline (322.676 us; speedup 1.0000x reference)
//
#include <hip/hip_runtime.h>

#define IMW 1024
#define IMH 1024
#define NB  8
#define HALF 25
#define VSTRIP 256
#define CTILE 64

#define W_R ((double)0.2989f)
#define W_G ((double)0.5870f)
#define W_B ((double)0.1140f)

__device__ __forceinline__ int refl(int i, int n) {
    if (i < 0) i = -i;
    if (i >= n) i = 2 * n - 2 - i;
    return i;
}

// 51-window sum at pixel p from inclusive row cumsum C[0..IMW-1], reflect pad.
__device__ __forceinline__ double wsum(const double* __restrict__ C, int p) {
    int a = p + HALF; if (a > IMW - 1) a = IMW - 1;
    int b = p - HALF - 1;
    double s = C[a] - (b >= 0 ? C[b] : 0.0);
    if (p <= HALF - 1)      s += C[HALF - p] - C[0];                        // i<0 mirrored
    if (p >= IMW - HALF)    s += C[IMW - 2] - C[2*IMW - 2 - HALF - 1 - p];  // i>=IMW mirrored
    return s;
}

// One block per image row. Cumsum of gray/gray^2 via register prefix + wave
// shuffle scan, 2-read window sums -> interleaved double2{h1,h2}. Per-block
// min/max -> plain store (no atomics).
__global__ __launch_bounds__(256) void k1_rowpass(const float* __restrict__ in,
                                                  double2* __restrict__ hp,
                                                  double2* __restrict__ blockstats) {
    __shared__ double cs1[IMW];
    __shared__ double cs2[IMW];
    __shared__ double wt1[4], wt2[4], bmin[4], bmax[4];
    const int row = blockIdx.x;                 // 0 .. NB*IMH-1
    const long long base = (long long)row * IMW;
    const int t = threadIdx.x;
    const int lane = t & 63, w = t >> 6;

    // 4 consecutive pixels per thread = 12 floats = 3x float4 (48B, 16B-aligned)
    const float4* p4 = (const float4*)(in + base * 3);
    float4 f0 = p4[3*t], f1 = p4[3*t+1], f2 = p4[3*t+2];
    double g0 = (double)f0.x*W_R + (double)f0.y*W_G + (double)f0.z*W_B;
    double g1 = (double)f0.w*W_R + (double)f1.x*W_G + (double)f1.y*W_B;
    double g2 = (double)f1.z*W_R + (double)f1.w*W_G + (double)f2.x*W_B;
    double g3 = (double)f2.y*W_R + (double)f2.z*W_G + (double)f2.w*W_B;

    double l1_0 = g0, l1_1 = l1_0 + g1, l1_2 = l1_1 + g2, l1_3 = l1_2 + g3;
    double q0 = g0*g0, q1 = g1*g1, q2 = g2*g2, q3 = g3*g3;
    double l2_0 = q0, l2_1 = l2_0 + q1, l2_2 = l2_1 + q2, l2_3 = l2_2 + q3;

    // block min/max
    double lmin = fmin(fmin(g0, g1), fmin(g2, g3));
    double lmax = fmax(fmax(g0, g1), fmax(g2, g3));
    for (int off = 32; off; off >>= 1) {
        lmin = fmin(lmin, __shfl_down(lmin, off));
        lmax = fmax(lmax, __shfl_down(lmax, off));
    }
    if (lane == 0) { bmin[w] = lmin; bmax[w] = lmax; }

    // wave-level inclusive scan of per-thread totals
    double v1 = l1_3, v2 = l2_3;
    for (int off = 1; off < 64; off <<= 1) {
        double u1 = __shfl_up(v1, off);
        double u2 = __shfl_up(v2, off);
        if (lane >= off) { v1 += u1; v2 += u2; }
    }
    if (lane == 63) { wt1[w] = v1; wt2[w] = v2; }
    __syncthreads();
    double e1 = v1 - l1_3, e2 = v2 - l2_3;   // exclusive prefix within wave
    for (int j = 0; j < w; j++) { e1 += wt1[j]; e2 += wt2[j]; }

    // write inclusive cumsum, 16B stores
    double2* c1 = (double2*)&cs1[4*t];
    double2* c2 = (double2*)&cs2[4*t];
    c1[0] = make_double2(e1 + l1_0, e1 + l1_1);
    c1[1] = make_double2(e1 + l1_2, e1 + l1_3);
    c2[0] = make_double2(e2 + l2_0, e2 + l2_1);
    c2[1] = make_double2(e2 + l2_2, e2 + l2_3);

    if (t == 0) {
        double m0 = fmin(fmin(bmin[0], bmin[1]), fmin(bmin[2], bmin[3]));
        double m1 = fmax(fmax(bmax[0], bmax[1]), fmax(bmax[2], bmax[3]));
        blockstats[row] = make_double2(m0, m1);
    }
    __syncthreads();

    // interleaved {h1,h2} -> 16B/lane coalesced stores
    for (int k = 0; k < 4; k++) {
        int p = t + 256 * k;
        hp[base + p] = make_double2(wsum(cs1, p), wsum(cs2, p));
    }
}

// Single-block tree reduce of 8192 per-row {min,max} pairs -> stats[0..1].
__global__ __launch_bounds__(1024) void k1b_reduce(const double2* __restrict__ blockstats,
                                                   double* __restrict__ stats) {
    __shared__ double smin[16], smax[16];
    const int t = threadIdx.x, lane = t & 63, w = t >> 6;
    double mn = 1e300, mx = -1e300;
    for (int i = t; i < NB * IMH; i += 1024) {
        double2 v = blockstats[i];
        mn = fmin(mn, v.x);
        mx = fmax(mx, v.y);
    }
    for (int off = 32; off; off >>= 1) {
        mn = fmin(mn, __shfl_down(mn, off));
        mx = fmax(mx, __shfl_down(mx, off));
    }
    if (lane == 0) { smin[w] = mn; smax[w] = mx; }
    __syncthreads();
    if (t == 0) {
        double a = smin[0], b = smax[0];
        for (int j = 1; j < 16; j++) { a = fmin(a, smin[j]); b = fmax(b, smax[j]); }
        stats[0] = a;
        stats[1] = b;
    }
}

// Streaming column pass: one thread per column, VSTRIP output rows per block.
// Last 51 h-rows live in an LDS ring; each thread owns its column's slots, so
// NO barriers. h element read (VSTRIP+50)/VSTRIP ~= 1.2x instead of 3.6x.
__global__ __launch_bounds__(CTILE) void k2_stream(const float* __restrict__ in,
                                                   const double2* __restrict__ hp,
                                                   const double* __restrict__ stats,
                                                   float* __restrict__ out) {
    __shared__ double2 ring[51][CTILE];
    const int c  = threadIdx.x;
    const int x  = blockIdx.x * CTILE + c;
    const int y0 = blockIdx.y * VSTRIP;
    const int b  = blockIdx.z;
    const long long ib = (long long)b * IMH * IMW;

    const double r = 0.5 * (stats[1] - stats[0]);

    double V1 = 0.0, V2 = 0.0;
    int slot = 0;

    // software pipeline: keep next h-row load in flight
    double2 h = hp[ib + (long long)refl(y0 - HALF, IMH) * IMW + x];

    for (int k = 0; k < VSTRIP + 2 * HALF; k++) {
        double2 hn = h;
        if (k + 1 < VSTRIP + 2 * HALF) {
            int ry = refl(y0 - HALF + k + 1, IMH);
            hn = hp[ib + (long long)ry * IMW + x];
        }

        double2 old = make_double2(0.0, 0.0);
        if (k >= 51) old = ring[slot][c];
        V1 += h.x - old.x;
        V2 += h.y - old.y;
        ring[slot][c] = h;

        if (k >= 2 * HALF) {
            int y = y0 + k - 2 * HALF;
            double m   = V1 / 2601.0;
            double m2  = V2 / 2601.0;
            double sd  = sqrt(fmax(m2 - m * m, 0.0));
            double th  = m * (1.0 + 0.2 * (sd / r - 1.0));
            long long pix = ib + (long long)y * IMW + x;
            const float* p = in + pix * 3;
            double g = (double)p[0]*W_R + (double)p[1]*W_G + (double)p[2]*W_B;
            out[pix] = (g > th) ? 1.0f : 0.0f;
        }

        slot = (slot + 1 == 51) ? 0 : slot + 1;
        h = hn;
    }
}

extern "C" void kernel_launch(void* const* d_in, const int* in_sizes, int n_in,
                              void* d_out, int out_size, void* d_ws, size_t ws_size,
                              hipStream_t stream) {
    const float* in = (const float*)d_in[0];
    float* out = (float*)d_out;

    double* stats = (double*)d_ws;                              // 2 doubles
    double2* blockstats = (double2*)((char*)d_ws + 256);        // 8192 double2
    double2* hp = (double2*)((char*)d_ws + (1 << 20));          // 134 MB interleaved {h1,h2}

    hipLaunchKernelGGL(k1_rowpass, dim3(NB * IMH), dim3(256), 0, stream,
                       in, hp, blockstats);
    hipLaunchKernelGGL(k1b_reduce, dim3(1), dim3(1024), 0, stream,
                       blockstats, stats);
    hipLaunchKernelGGL(k2_stream, dim3(IMW / CTILE, IMH / VSTRIP, NB), dim3(CTILE), 0, stream,
                       in, hp, stats, out);
}

// Round 5
// 285.124 us; speedup vs baseline: 1.1317x; 1.1317x over previous
//
#include <hip/hip_runtime.h>

#define IMW 1024
#define IMH 1024
#define NB  8
#define HALF 25
#define STRIP 16
#define NCELL 64

#define W_R ((double)0.2989f)
#define W_G ((double)0.5870f)
#define W_B ((double)0.1140f)

__device__ __forceinline__ int refl(int i, int n) {
    if (i < 0) i = -i;
    if (i >= n) i = 2 * n - 2 - i;
    return i;
}

// 51-window sum at pixel p from inclusive row cumsum C[0..IMW-1], reflect pad.
__device__ __forceinline__ double wsum(const double* __restrict__ C, int p) {
    int a = p + HALF; if (a > IMW - 1) a = IMW - 1;
    int b = p - HALF - 1;
    double s = C[a] - (b >= 0 ? C[b] : 0.0);
    if (p <= HALF - 1)      s += C[HALF - p] - C[0];                        // i<0 mirrored
    if (p >= IMW - HALF)    s += C[IMW - 2] - C[2*IMW - 2 - HALF - 1 - p];  // i>=IMW mirrored
    return s;
}

// init 64 min-cells (all-ones) and 64 max-cells (zero); gray>=0 so bit-order == double order
__global__ void k0_init(unsigned long long* cells) {
    cells[threadIdx.x] = ~0ULL;          // min cells
    cells[NCELL + threadIdx.x] = 0ULL;   // max cells
}

// One block per image row. Cumsum of gray/gray^2 via register prefix + wave
// shuffle scan, 2-read window sums -> interleaved double2{h1,h2}.
// Min/max via hierarchical atomics over 64 cells (~128 ops/cell, parallel).
__global__ __launch_bounds__(256) void k1_rowpass(const float* __restrict__ in,
                                                  double2* __restrict__ hp,
                                                  unsigned long long* __restrict__ cells) {
    __shared__ double cs1[IMW];
    __shared__ double cs2[IMW];
    __shared__ double wt1[4], wt2[4], bmin[4], bmax[4];
    const int row = blockIdx.x;                 // 0 .. NB*IMH-1
    const long long base = (long long)row * IMW;
    const int t = threadIdx.x;
    const int lane = t & 63, w = t >> 6;

    // 4 consecutive pixels per thread = 12 floats = 3x float4 (48B, 16B-aligned)
    const float4* p4 = (const float4*)(in + base * 3);
    float4 f0 = p4[3*t], f1 = p4[3*t+1], f2 = p4[3*t+2];
    double g0 = (double)f0.x*W_R + (double)f0.y*W_G + (double)f0.z*W_B;
    double g1 = (double)f0.w*W_R + (double)f1.x*W_G + (double)f1.y*W_B;
    double g2 = (double)f1.z*W_R + (double)f1.w*W_G + (double)f2.x*W_B;
    double g3 = (double)f2.y*W_R + (double)f2.z*W_G + (double)f2.w*W_B;

    double l1_0 = g0, l1_1 = l1_0 + g1, l1_2 = l1_1 + g2, l1_3 = l1_2 + g3;
    double q0 = g0*g0, q1 = g1*g1, q2 = g2*g2, q3 = g3*g3;
    double l2_0 = q0, l2_1 = l2_0 + q1, l2_2 = l2_1 + q2, l2_3 = l2_2 + q3;

    // block min/max
    double lmin = fmin(fmin(g0, g1), fmin(g2, g3));
    double lmax = fmax(fmax(g0, g1), fmax(g2, g3));
    for (int off = 32; off; off >>= 1) {
        lmin = fmin(lmin, __shfl_down(lmin, off));
        lmax = fmax(lmax, __shfl_down(lmax, off));
    }
    if (lane == 0) { bmin[w] = lmin; bmax[w] = lmax; }

    // wave-level inclusive scan of per-thread totals
    double v1 = l1_3, v2 = l2_3;
    for (int off = 1; off < 64; off <<= 1) {
        double u1 = __shfl_up(v1, off);
        double u2 = __shfl_up(v2, off);
        if (lane >= off) { v1 += u1; v2 += u2; }
    }
    if (lane == 63) { wt1[w] = v1; wt2[w] = v2; }
    __syncthreads();
    double e1 = v1 - l1_3, e2 = v2 - l2_3;   // exclusive prefix within wave
    for (int j = 0; j < w; j++) { e1 += wt1[j]; e2 += wt2[j]; }

    // write inclusive cumsum, 16B stores
    double2* c1 = (double2*)&cs1[4*t];
    double2* c2 = (double2*)&cs2[4*t];
    c1[0] = make_double2(e1 + l1_0, e1 + l1_1);
    c1[1] = make_double2(e1 + l1_2, e1 + l1_3);
    c2[0] = make_double2(e2 + l2_0, e2 + l2_1);
    c2[1] = make_double2(e2 + l2_2, e2 + l2_3);

    if (t == 0) {
        double m0 = fmin(fmin(bmin[0], bmin[1]), fmin(bmin[2], bmin[3]));
        double m1 = fmax(fmax(bmax[0], bmax[1]), fmax(bmax[2], bmax[3]));
        int cell = row & (NCELL - 1);   // adjacent rows -> different cells
        atomicMin(&cells[cell], (unsigned long long)__double_as_longlong(m0));
        atomicMax(&cells[NCELL + cell], (unsigned long long)__double_as_longlong(m1));
    }
    __syncthreads();

    // interleaved {h1,h2} -> 16B/lane coalesced stores
    for (int k = 0; k < 4; k++) {
        int p = t + 256 * k;
        hp[base + p] = make_double2(wsum(cs1, p), wsum(cs2, p));
    }
}

// Column pass: 2 columns/thread, vertical running 51-window over interleaved hp.
// Prologue reduces the 64 min/max cells (L2-hot, ~1KB) -> r.
__global__ __launch_bounds__(256) void k2_colpass(const float* __restrict__ in,
                                                  const double2* __restrict__ hp,
                                                  const unsigned long long* __restrict__ cells,
                                                  float* __restrict__ out) {
    __shared__ double sr[2];
    const int t = threadIdx.x;
    if (t < 64) {
        unsigned long long mn = cells[t];
        unsigned long long mx = cells[NCELL + t];
        for (int off = 32; off; off >>= 1) {
            unsigned long long a = __shfl_down(mn, off);
            unsigned long long b = __shfl_down(mx, off);
            mn = (a < mn) ? a : mn;
            mx = (b > mx) ? b : mx;
        }
        if (t == 0) {
            sr[0] = __longlong_as_double((long long)mn);
            sr[1] = __longlong_as_double((long long)mx);
        }
    }
    __syncthreads();
    const double r = 0.5 * (sr[1] - sr[0]);

    const int x0 = (blockIdx.x * 256 + t) * 2;
    const int y0 = blockIdx.y * STRIP;
    const int b  = blockIdx.z;
    const long long ib = (long long)b * IMH * IMW;

    double2 vA = make_double2(0.0, 0.0);   // {h1,h2} running sums, col a
    double2 vB = make_double2(0.0, 0.0);   // col b
    for (int j = -HALF; j <= HALF; j++) {
        int ry = refl(y0 + j, IMH);
        long long idx = ib + (long long)ry * IMW + x0;
        double2 ha = hp[idx];
        double2 hb = hp[idx + 1];
        vA.x += ha.x; vA.y += ha.y;
        vB.x += hb.x; vB.y += hb.y;
    }

    for (int y = y0; y < y0 + STRIP; y++) {
        long long pix = ib + (long long)y * IMW + x0;
        // 2 pixels = 6 floats, 8B-aligned: 3x float2
        const float2* p2 = (const float2*)(in + pix * 3);
        float2 a0 = p2[0], a1 = p2[1], a2 = p2[2];
        double ga = (double)a0.x*W_R + (double)a0.y*W_G + (double)a1.x*W_B;
        double gb = (double)a1.y*W_R + (double)a2.x*W_G + (double)a2.y*W_B;

        double m_a  = vA.x / 2601.0, m_b  = vB.x / 2601.0;
        double m2_a = vA.y / 2601.0, m2_b = vB.y / 2601.0;
        double sd_a = sqrt(fmax(m2_a - m_a * m_a, 0.0));
        double sd_b = sqrt(fmax(m2_b - m_b * m_b, 0.0));
        double th_a = m_a * (1.0 + 0.2 * (sd_a / r - 1.0));
        double th_b = m_b * (1.0 + 0.2 * (sd_b / r - 1.0));
        *(float2*)(out + pix) = make_float2(ga > th_a ? 1.0f : 0.0f,
                                            gb > th_b ? 1.0f : 0.0f);

        int ra = refl(y + HALF + 1, IMH);
        int rs = refl(y - HALF, IMH);
        long long iadd = ib + (long long)ra * IMW + x0;
        long long isub = ib + (long long)rs * IMW + x0;
        double2 aa = hp[iadd],     as = hp[isub];
        double2 ba = hp[iadd + 1], bs = hp[isub + 1];
        vA.x += aa.x - as.x;  vA.y += aa.y - as.y;
        vB.x += ba.x - bs.x;  vB.y += ba.y - bs.y;
    }
}

extern "C" void kernel_launch(void* const* d_in, const int* in_sizes, int n_in,
                              void* d_out, int out_size, void* d_ws, size_t ws_size,
                              hipStream_t stream) {
    const float* in = (const float*)d_in[0];
    float* out = (float*)d_out;

    unsigned long long* cells = (unsigned long long*)d_ws;      // 2*64 u64
    double2* hp = (double2*)((char*)d_ws + 4096);               // 134 MB interleaved {h1,h2}

    hipLaunchKernelGGL(k0_init, dim3(1), dim3(NCELL), 0, stream, cells);
    hipLaunchKernelGGL(k1_rowpass, dim3(NB * IMH), dim3(256), 0, stream,
                       in, hp, cells);
    hipLaunchKernelGGL(k2_colpass, dim3(IMW / 512, IMH / STRIP, NB), dim3(256), 0, stream,
                       in, hp, cells, out);
}

// Round 6
// 257.334 us; speedup vs baseline: 1.2539x; 1.1080x over previous
//
#include <hip/hip_runtime.h>

#define IMW 1024
#define IMH 1024
#define NB  8
#define HALF 25
#define STRIP 32
#define NCELL 64

#define W_R ((double)0.2989f)
#define W_G ((double)0.5870f)
#define W_B ((double)0.1140f)
#define INV_AREA (1.0 / 2601.0)

__device__ __forceinline__ int refl(int i, int n) {
    if (i < 0) i = -i;
    if (i >= n) i = 2 * n - 2 - i;
    return i;
}

// 51-window sum at pixel p from inclusive row cumsum C[0..IMW-1], reflect pad.
__device__ __forceinline__ double wsum(const double* __restrict__ C, int p) {
    int a = p + HALF; if (a > IMW - 1) a = IMW - 1;
    int b = p - HALF - 1;
    double s = C[a] - (b >= 0 ? C[b] : 0.0);
    if (p <= HALF - 1)      s += C[HALF - p] - C[0];                        // i<0 mirrored
    if (p >= IMW - HALF)    s += C[IMW - 2] - C[2*IMW - 2 - HALF - 1 - p];  // i>=IMW mirrored
    return s;
}

// init 64 min-cells (all-ones) and 64 max-cells (zero); gray>=0 so bit-order == double order
__global__ void k0_init(unsigned long long* cells) {
    cells[threadIdx.x] = ~0ULL;          // min cells
    cells[NCELL + threadIdx.x] = 0ULL;   // max cells
}

// One block per image row. Cumsum of gray/gray^2 via register prefix + wave
// shuffle scan, 2-read window sums -> interleaved double2{h1,h2}.
// Min/max via hierarchical atomics over 64 cells (~128 ops/cell, parallel).
__global__ __launch_bounds__(256) void k1_rowpass(const float* __restrict__ in,
                                                  double2* __restrict__ hp,
                                                  unsigned long long* __restrict__ cells) {
    __shared__ double cs1[IMW];
    __shared__ double cs2[IMW];
    __shared__ double wt1[4], wt2[4], bmin[4], bmax[4];
    const int row = blockIdx.x;                 // 0 .. NB*IMH-1
    const long long base = (long long)row * IMW;
    const int t = threadIdx.x;
    const int lane = t & 63, w = t >> 6;

    // 4 consecutive pixels per thread = 12 floats = 3x float4 (48B, 16B-aligned)
    const float4* p4 = (const float4*)(in + base * 3);
    float4 f0 = p4[3*t], f1 = p4[3*t+1], f2 = p4[3*t+2];
    double g0 = (double)f0.x*W_R + (double)f0.y*W_G + (double)f0.z*W_B;
    double g1 = (double)f0.w*W_R + (double)f1.x*W_G + (double)f1.y*W_B;
    double g2 = (double)f1.z*W_R + (double)f1.w*W_G + (double)f2.x*W_B;
    double g3 = (double)f2.y*W_R + (double)f2.z*W_G + (double)f2.w*W_B;

    double l1_0 = g0, l1_1 = l1_0 + g1, l1_2 = l1_1 + g2, l1_3 = l1_2 + g3;
    double q0 = g0*g0, q1 = g1*g1, q2 = g2*g2, q3 = g3*g3;
    double l2_0 = q0, l2_1 = l2_0 + q1, l2_2 = l2_1 + q2, l2_3 = l2_2 + q3;

    // block min/max
    double lmin = fmin(fmin(g0, g1), fmin(g2, g3));
    double lmax = fmax(fmax(g0, g1), fmax(g2, g3));
    for (int off = 32; off; off >>= 1) {
        lmin = fmin(lmin, __shfl_down(lmin, off));
        lmax = fmax(lmax, __shfl_down(lmax, off));
    }
    if (lane == 0) { bmin[w] = lmin; bmax[w] = lmax; }

    // wave-level inclusive scan of per-thread totals
    double v1 = l1_3, v2 = l2_3;
    for (int off = 1; off < 64; off <<= 1) {
        double u1 = __shfl_up(v1, off);
        double u2 = __shfl_up(v2, off);
        if (lane >= off) { v1 += u1; v2 += u2; }
    }
    if (lane == 63) { wt1[w] = v1; wt2[w] = v2; }
    __syncthreads();
    double e1 = v1 - l1_3, e2 = v2 - l2_3;   // exclusive prefix within wave
    for (int j = 0; j < w; j++) { e1 += wt1[j]; e2 += wt2[j]; }

    // write inclusive cumsum, 16B stores
    double2* c1 = (double2*)&cs1[4*t];
    double2* c2 = (double2*)&cs2[4*t];
    c1[0] = make_double2(e1 + l1_0, e1 + l1_1);
    c1[1] = make_double2(e1 + l1_2, e1 + l1_3);
    c2[0] = make_double2(e2 + l2_0, e2 + l2_1);
    c2[1] = make_double2(e2 + l2_2, e2 + l2_3);

    if (t == 0) {
        double m0 = fmin(fmin(bmin[0], bmin[1]), fmin(bmin[2], bmin[3]));
        double m1 = fmax(fmax(bmax[0], bmax[1]), fmax(bmax[2], bmax[3]));
        int cell = row & (NCELL - 1);   // adjacent rows -> different cells
        atomicMin(&cells[cell], (unsigned long long)__double_as_longlong(m0));
        atomicMax(&cells[NCELL + cell], (unsigned long long)__double_as_longlong(m1));
    }
    __syncthreads();

    // interleaved {h1,h2} -> 16B/lane coalesced stores
    for (int k = 0; k < 4; k++) {
        int p = t + 256 * k;
        hp[base + p] = make_double2(wsum(cs1, p), wsum(cs2, p));
    }
}

// Column pass: 2 columns/thread, vertical running 51-window over interleaved hp.
// XCD-swizzled linear grid: batch = id&7 (one image per XCD -> L2-local hp
// stream, adjacent y-strips dispatch consecutively on the same XCD).
// Sqrt/div-free Sauvola compare: g > m(1+0.2(s/r-1)) <=> A>0 && A^2 r^2 > 0.04 m^2 var.
__global__ __launch_bounds__(256) void k2_colpass(const float* __restrict__ in,
                                                  const double2* __restrict__ hp,
                                                  const unsigned long long* __restrict__ cells,
                                                  float* __restrict__ out) {
    __shared__ double sr[2];
    const int t = threadIdx.x;
    if (t < 64) {
        unsigned long long mn = cells[t];
        unsigned long long mx = cells[NCELL + t];
        for (int off = 32; off; off >>= 1) {
            unsigned long long a = __shfl_down(mn, off);
            unsigned long long b = __shfl_down(mx, off);
            mn = (a < mn) ? a : mn;
            mx = (b > mx) ? b : mx;
        }
        if (t == 0) {
            sr[0] = __longlong_as_double((long long)mn);
            sr[1] = __longlong_as_double((long long)mx);
        }
    }
    __syncthreads();
    const double r  = 0.5 * (sr[1] - sr[0]);
    const double r2 = r * r;

    const int id   = blockIdx.x;          // 512 blocks
    const int b    = id & 7;              // batch -> XCD
    const int rest = id >> 3;
    const int ys   = rest & 31;           // y-strip (consecutive on same XCD)
    const int xc   = rest >> 5;           // x half
    const int x0 = (xc * 256 + t) * 2;
    const int y0 = ys * STRIP;
    const long long ib = (long long)b * IMH * IMW;

    double2 vA = make_double2(0.0, 0.0);   // {h1,h2} running sums, col a
    double2 vB = make_double2(0.0, 0.0);   // col b
    for (int j = -HALF; j <= HALF; j++) {
        int ry = refl(y0 + j, IMH);
        long long idx = ib + (long long)ry * IMW + x0;
        double2 ha = hp[idx];
        double2 hb = hp[idx + 1];
        vA.x += ha.x; vA.y += ha.y;
        vB.x += hb.x; vB.y += hb.y;
    }

    #pragma unroll 4
    for (int y = y0; y < y0 + STRIP; y++) {
        long long pix = ib + (long long)y * IMW + x0;
        // 2 pixels = 6 floats, 8B-aligned: 3x float2
        const float2* p2 = (const float2*)(in + pix * 3);
        float2 a0 = p2[0], a1 = p2[1], a2 = p2[2];
        double ga = (double)a0.x*W_R + (double)a0.y*W_G + (double)a1.x*W_B;
        double gb = (double)a1.y*W_R + (double)a2.x*W_G + (double)a2.y*W_B;

        double m_a  = vA.x * INV_AREA, m_b  = vB.x * INV_AREA;
        double va_a = fmax(vA.y * INV_AREA - m_a * m_a, 0.0);
        double va_b = fmax(vB.y * INV_AREA - m_b * m_b, 0.0);
        double A_a  = ga - 0.8 * m_a;
        double A_b  = gb - 0.8 * m_b;
        int oa = (A_a > 0.0) && (A_a * A_a * r2 > 0.04 * m_a * m_a * va_a);
        int ob = (A_b > 0.0) && (A_b * A_b * r2 > 0.04 * m_b * m_b * va_b);
        *(float2*)(out + pix) = make_float2(oa ? 1.0f : 0.0f, ob ? 1.0f : 0.0f);

        int ra = refl(y + HALF + 1, IMH);
        int rs = refl(y - HALF, IMH);
        long long iadd = ib + (long long)ra * IMW + x0;
        long long isub = ib + (long long)rs * IMW + x0;
        double2 aa = hp[iadd],     as = hp[isub];
        double2 ba = hp[iadd + 1], bs = hp[isub + 1];
        vA.x += aa.x - as.x;  vA.y += aa.y - as.y;
        vB.x += ba.x - bs.x;  vB.y += ba.y - bs.y;
    }
}

extern "C" void kernel_launch(void* const* d_in, const int* in_sizes, int n_in,
                              void* d_out, int out_size, void* d_ws, size_t ws_size,
                              hipStream_t stream) {
    const float* in = (const float*)d_in[0];
    float* out = (float*)d_out;

    unsigned long long* cells = (unsigned long long*)d_ws;      // 2*64 u64
    double2* hp = (double2*)((char*)d_ws + 4096);               // 134 MB interleaved {h1,h2}

    hipLaunchKernelGGL(k0_init, dim3(1), dim3(NCELL), 0, stream, cells);
    hipLaunchKernelGGL(k1_rowpass, dim3(NB * IMH), dim3(256), 0, stream,
                       in, hp, cells);
    hipLaunchKernelGGL(k2_colpass, dim3((IMW / 512) * (IMH / STRIP) * NB), dim3(256), 0, stream,
                       in, hp, cells, out);
}

// Round 7
// 237.604 us; speedup vs baseline: 1.3580x; 1.0830x over previous
//
#include <hip/hip_runtime.h>

#define IMW 1024
#define IMH 1024
#define NB  8
#define HALF 25
#define STRIP 64
#define NCELL 64

#define W_R ((double)0.2989f)
#define W_G ((double)0.5870f)
#define W_B ((double)0.1140f)
#define INV_AREA (1.0 / 2601.0)

__device__ __forceinline__ int refl(int i, int n) {
    if (i < 0) i = -i;
    if (i >= n) i = 2 * n - 2 - i;
    return i;
}

// 51-window sum at pixel p from inclusive row cumsum C[0..IMW-1], reflect pad.
__device__ __forceinline__ double wsum(const double* __restrict__ C, int p) {
    int a = p + HALF; if (a > IMW - 1) a = IMW - 1;
    int b = p - HALF - 1;
    double s = C[a] - (b >= 0 ? C[b] : 0.0);
    if (p <= HALF - 1)      s += C[HALF - p] - C[0];                        // i<0 mirrored
    if (p >= IMW - HALF)    s += C[IMW - 2] - C[2*IMW - 2 - HALF - 1 - p];  // i>=IMW mirrored
    return s;
}

// init 64 min-cells (all-ones) and 64 max-cells (zero); gray>=0 so bit-order == double order
__global__ void k0_init(unsigned long long* cells) {
    cells[threadIdx.x] = ~0ULL;          // min cells
    cells[NCELL + threadIdx.x] = 0ULL;   // max cells
}

// One block per image row. Cumsum of gray/gray^2 via register prefix + wave
// shuffle scan, 2-read window sums -> interleaved double2{h1,h2}.
// Min/max via hierarchical atomics over 64 cells (~128 ops/cell, parallel).
__global__ __launch_bounds__(256) void k1_rowpass(const float* __restrict__ in,
                                                  double2* __restrict__ hp,
                                                  unsigned long long* __restrict__ cells) {
    __shared__ double cs1[IMW];
    __shared__ double cs2[IMW];
    __shared__ double wt1[4], wt2[4], bmin[4], bmax[4];
    const int row = blockIdx.x;                 // 0 .. NB*IMH-1
    const long long base = (long long)row * IMW;
    const int t = threadIdx.x;
    const int lane = t & 63, w = t >> 6;

    // 4 consecutive pixels per thread = 12 floats = 3x float4 (48B, 16B-aligned)
    const float4* p4 = (const float4*)(in + base * 3);
    float4 f0 = p4[3*t], f1 = p4[3*t+1], f2 = p4[3*t+2];
    double g0 = (double)f0.x*W_R + (double)f0.y*W_G + (double)f0.z*W_B;
    double g1 = (double)f0.w*W_R + (double)f1.x*W_G + (double)f1.y*W_B;
    double g2 = (double)f1.z*W_R + (double)f1.w*W_G + (double)f2.x*W_B;
    double g3 = (double)f2.y*W_R + (double)f2.z*W_G + (double)f2.w*W_B;

    double l1_0 = g0, l1_1 = l1_0 + g1, l1_2 = l1_1 + g2, l1_3 = l1_2 + g3;
    double q0 = g0*g0, q1 = g1*g1, q2 = g2*g2, q3 = g3*g3;
    double l2_0 = q0, l2_1 = l2_0 + q1, l2_2 = l2_1 + q2, l2_3 = l2_2 + q3;

    // block min/max
    double lmin = fmin(fmin(g0, g1), fmin(g2, g3));
    double lmax = fmax(fmax(g0, g1), fmax(g2, g3));
    for (int off = 32; off; off >>= 1) {
        lmin = fmin(lmin, __shfl_down(lmin, off));
        lmax = fmax(lmax, __shfl_down(lmax, off));
    }
    if (lane == 0) { bmin[w] = lmin; bmax[w] = lmax; }

    // wave-level inclusive scan of per-thread totals
    double v1 = l1_3, v2 = l2_3;
    for (int off = 1; off < 64; off <<= 1) {
        double u1 = __shfl_up(v1, off);
        double u2 = __shfl_up(v2, off);
        if (lane >= off) { v1 += u1; v2 += u2; }
    }
    if (lane == 63) { wt1[w] = v1; wt2[w] = v2; }
    __syncthreads();
    double e1 = v1 - l1_3, e2 = v2 - l2_3;   // exclusive prefix within wave
    for (int j = 0; j < w; j++) { e1 += wt1[j]; e2 += wt2[j]; }

    // write inclusive cumsum, 16B stores
    double2* c1 = (double2*)&cs1[4*t];
    double2* c2 = (double2*)&cs2[4*t];
    c1[0] = make_double2(e1 + l1_0, e1 + l1_1);
    c1[1] = make_double2(e1 + l1_2, e1 + l1_3);
    c2[0] = make_double2(e2 + l2_0, e2 + l2_1);
    c2[1] = make_double2(e2 + l2_2, e2 + l2_3);

    if (t == 0) {
        double m0 = fmin(fmin(bmin[0], bmin[1]), fmin(bmin[2], bmin[3]));
        double m1 = fmax(fmax(bmax[0], bmax[1]), fmax(bmax[2], bmax[3]));
        int cell = row & (NCELL - 1);   // adjacent rows -> different cells
        atomicMin(&cells[cell], (unsigned long long)__double_as_longlong(m0));
        atomicMax(&cells[NCELL + cell], (unsigned long long)__double_as_longlong(m1));
    }
    __syncthreads();

    // interleaved {h1,h2} -> 16B/lane coalesced stores
    for (int k = 0; k < 4; k++) {
        int p = t + 256 * k;
        hp[base + p] = make_double2(wsum(cs1, p), wsum(cs2, p));
    }
}

// Column pass: 1 column/thread, vertical running 51-window over interleaved hp.
// STRIP=64 cuts window re-init traffic to (51+128)/64 = 2.8 rows/output.
// XCD-swizzled linear grid: batch = id&7 -> one image per XCD.
// Sqrt/div-free Sauvola compare: g > m(1+0.2(s/r-1)) <=> A>0 && A^2 r^2 > 0.04 m^2 var.
__global__ __launch_bounds__(256) void k2_colpass(const float* __restrict__ in,
                                                  const double2* __restrict__ hp,
                                                  const unsigned long long* __restrict__ cells,
                                                  float* __restrict__ out) {
    __shared__ double sr[2];
    const int t = threadIdx.x;
    if (t < 64) {
        unsigned long long mn = cells[t];
        unsigned long long mx = cells[NCELL + t];
        for (int off = 32; off; off >>= 1) {
            unsigned long long a = __shfl_down(mn, off);
            unsigned long long b = __shfl_down(mx, off);
            mn = (a < mn) ? a : mn;
            mx = (b > mx) ? b : mx;
        }
        if (t == 0) {
            sr[0] = __longlong_as_double((long long)mn);
            sr[1] = __longlong_as_double((long long)mx);
        }
    }
    __syncthreads();
    const double r  = 0.5 * (sr[1] - sr[0]);
    const double r2 = r * r;

    const int id   = blockIdx.x;          // 512 blocks
    const int b    = id & 7;              // batch -> XCD
    const int rest = id >> 3;
    const int ys   = rest & 15;           // y-strip (consecutive on same XCD)
    const int xc   = rest >> 4;           // x quarter (0..3)
    const int x  = xc * 256 + t;          // 1 column per thread
    const int y0 = ys * STRIP;
    const long long ib = (long long)b * IMH * IMW;

    double2 v = make_double2(0.0, 0.0);   // {h1,h2} running vertical sums
    #pragma unroll 8
    for (int j = -HALF; j <= HALF; j++) {
        int ry = refl(y0 + j, IMH);
        double2 h = hp[ib + (long long)ry * IMW + x];
        v.x += h.x; v.y += h.y;
    }

    #pragma unroll 8
    for (int y = y0; y < y0 + STRIP; y++) {
        long long pix = ib + (long long)y * IMW + x;
        const float* p = in + pix * 3;
        double g = (double)p[0]*W_R + (double)p[1]*W_G + (double)p[2]*W_B;

        double m  = v.x * INV_AREA;
        double va = fmax(v.y * INV_AREA - m * m, 0.0);
        double A  = g - 0.8 * m;
        int o = (A > 0.0) && (A * A * r2 > 0.04 * m * m * va);
        out[pix] = o ? 1.0f : 0.0f;

        int ra = refl(y + HALF + 1, IMH);
        int rs = refl(y - HALF, IMH);
        double2 ha = hp[ib + (long long)ra * IMW + x];
        double2 hs = hp[ib + (long long)rs * IMW + x];
        v.x += ha.x - hs.x;
        v.y += ha.y - hs.y;
    }
}

extern "C" void kernel_launch(void* const* d_in, const int* in_sizes, int n_in,
                              void* d_out, int out_size, void* d_ws, size_t ws_size,
                              hipStream_t stream) {
    const float* in = (const float*)d_in[0];
    float* out = (float*)d_out;

    unsigned long long* cells = (unsigned long long*)d_ws;      // 2*64 u64
    double2* hp = (double2*)((char*)d_ws + 4096);               // 134 MB interleaved {h1,h2}

    hipLaunchKernelGGL(k0_init, dim3(1), dim3(NCELL), 0, stream, cells);
    hipLaunchKernelGGL(k1_rowpass, dim3(NB * IMH), dim3(256), 0, stream,
                       in, hp, cells);
    hipLaunchKernelGGL(k2_colpass, dim3((IMW / 256) * (IMH / STRIP) * NB), dim3(256), 0, stream,
                       in, hp, cells, out);
}